// Round 3
// baseline (660.570 us; speedup 1.0000x reference)
//
#include <hip/hip_runtime.h>
#include <hip/hip_bf16.h>
#include <stdint.h>

// Problem dims
#define P_ 64
#define N_ 256
#define F_ 4096
#define H_ 512
#define O_ 64

#define FT 128   // cells per block (f-tile)
#define HC 128   // h-chunk
#define KC 64    // n-chunk for W1' staging

using fragA = __attribute__((ext_vector_type(8))) short;   // 8 bf16
using fragC = __attribute__((ext_vector_type(4))) float;   // 4 f32

__device__ __forceinline__ short f2bf(float f) {
    union { float f; unsigned u; } v; v.f = f;
    unsigned r = v.u + 0x7fffu + ((v.u >> 16) & 1u);   // RNE
    return (short)(r >> 16);
}

__device__ __forceinline__ void gload_lds16(const void* g, void* l) {
    __builtin_amdgcn_global_load_lds(
        (const __attribute__((address_space(1))) unsigned*)g,
        (__attribute__((address_space(3))) unsigned*)l,
        16, 0, 0);
}

// hlds swizzle: conflict-free on BOTH the (lg-spread) write and (lr-spread) read
__device__ __forceinline__ int hswz(int frow) {
    return (((frow >> 2) & 3) ^ (frow & 3)) << 4;
}

// ---------------- transpose + f32->bf16 convert:  in[B][R][C] -> out[B][C][R]
__global__ __launch_bounds__(256) void k_transpose_cvt(
    const float* __restrict__ in, short* __restrict__ out, int R, int C)
{
    __shared__ float t[32][33];
    int b = blockIdx.z;
    int tx = threadIdx.x & 31, ty = threadIdx.x >> 5;
    int r0 = blockIdx.y * 32, c0 = blockIdx.x * 32;
    const float* ip = in + ((size_t)b * R + r0) * C + c0;
    #pragma unroll
    for (int i = 0; i < 4; ++i)
        t[ty + 8*i][tx] = ip[(size_t)(ty + 8*i) * C + tx];
    __syncthreads();
    short* op = out + ((size_t)b * C + c0) * R + r0;
    #pragma unroll
    for (int i = 0; i < 4; ++i)
        op[(size_t)(ty + 8*i) * R + tx] = f2bf(t[tx][ty + 8*i]);
}

// ---------------- fold GEMM:  w1t[p][h][n] = sum_m W1T[p][h][m] * lplsT[p][n][m]
// (= (lpls^T @ W1) stored transposed, exactly the B-layout stage 2 wants)
__global__ __launch_bounds__(256) void k_fold(
    const short* __restrict__ w1T,    // [P][H][256] bf16 (m contiguous)
    const short* __restrict__ lplsT,  // [P][N][256] bf16 (m contiguous)
    short* __restrict__ w1t)          // [P][H][N] bf16
{
    int tid = threadIdx.x;
    int w = tid >> 6, l = tid & 63, lg = l >> 4, lr = l & 15;
    int bp = blockIdx.x;              // 64p * 4hb * 2nb = 512
    int p  = bp >> 3;
    int hb = ((bp >> 1) & 3) * 128;
    int nb = (bp & 1) * 128;
    int wr = w >> 1, wc = w & 1;

    const short* A = w1T   + (size_t)p * H_ * 256;
    const short* B = lplsT + (size_t)p * N_ * 256;

    fragC acc[4][4];
    #pragma unroll
    for (int i = 0; i < 4; ++i)
        #pragma unroll
        for (int j = 0; j < 4; ++j)
            acc[i][j] = fragC{0.f, 0.f, 0.f, 0.f};

    #pragma unroll
    for (int kk = 0; kk < 8; ++kk) {
        fragA af[4], bf[4];
        #pragma unroll
        for (int mi = 0; mi < 4; ++mi) {
            int h = hb + wr*64 + mi*16 + lr;
            af[mi] = *(const fragA*)&A[(size_t)h*256 + kk*32 + lg*8];
        }
        #pragma unroll
        for (int nj = 0; nj < 4; ++nj) {
            int n = nb + wc*64 + nj*16 + lr;
            bf[nj] = *(const fragA*)&B[(size_t)n*256 + kk*32 + lg*8];
        }
        #pragma unroll
        for (int mi = 0; mi < 4; ++mi)
            #pragma unroll
            for (int nj = 0; nj < 4; ++nj)
                acc[mi][nj] = __builtin_amdgcn_mfma_f32_16x16x32_bf16(
                    af[mi], bf[nj], acc[mi][nj], 0, 0, 0);
    }

    #pragma unroll
    for (int mi = 0; mi < 4; ++mi)
        #pragma unroll
        for (int nj = 0; nj < 4; ++nj)
            #pragma unroll
            for (int r = 0; r < 4; ++r) {
                int h = hb + wr*64 + mi*16 + lg*4 + r;
                int n = nb + wc*64 + nj*16 + lr;
                w1t[((size_t)(p*H_ + h)) * N_ + n] = f2bf(acc[mi][nj][r]);
            }
}

// ---------------- fused MLP:  out[p][f][o] = relu(exp^T @ W1' + b1) @ W2 + b2
// 2-phase pipelined staging: per step { vmcnt(0); bar; STAGE(s+1); compute(s) }.
// hlds is wave-private (rows w*16..w*16+15 only) -> no barriers around it.
__global__ __launch_bounds__(512) void k_mlp(
    const float* __restrict__ expm,   // [P][N][F] f32
    const short* __restrict__ w1t,    // [P][H][N] bf16  (W1'^T)
    const float* __restrict__ b1,     // [P][H]
    const short* __restrict__ w2t,    // [P][O][H] bf16  (W2^T)
    const float* __restrict__ b2,     // [P][O]
    float* __restrict__ out)          // [P][F][O] f32
{
    __shared__ __align__(16) short hlds[FT][HC];     // elem(f,h) at [f][h ^ hswz(f)]
    __shared__ __align__(16) short wbuf[2][HC][KC];  // elem(hl,ns) at [hl][ns ^ ((hl&7)<<3)]

    int tid = threadIdx.x;
    int w = tid >> 6, l = tid & 63, lg = l >> 4, lr = l & 15;
    int p  = blockIdx.x >> 5;             // 32 f-tiles per pathway
    int f0 = (blockIdx.x & 31) * FT;
    int fw = f0 + w*16 + lr;              // this lane's A-row (global f)

    // stage step s (= hc*4+kc) of W1' into wbuf[s&1]; swizzle baked into SOURCE addr
    auto STAGE = [&](int s) {
        int hcs = s >> 2, kcs = s & 3;
        #pragma unroll
        for (int i = 0; i < 2; ++i) {
            int lin = i*512 + tid;
            int hl  = lin >> 3;                     // chunk row
            int s8  = (lin & 7) * 8;                // linear dest 8-elem slot
            int nsg = s8 ^ ((hl & 7) << 3);         // source column for this slot
            const short* src = w1t + ((size_t)(p*H_ + hcs*HC + hl)) * N_ + kcs*KC + nsg;
            short* dst = &wbuf[s & 1][0][0] + i*4096 + w*512;  // wave-uniform base
            gload_lds16(src, dst);
        }
    };

    // ---- A hoist: exp fragments in registers (exp read exactly once) ----
    fragA a[8];
    const float* eb = expm + (size_t)p * N_ * F_ + fw;
    #pragma unroll
    for (int kk = 0; kk < 8; ++kk) {
        #pragma unroll
        for (int e = 0; e < 8; ++e) {
            int n = kk*32 + lg*8 + e;
            a[kk][e] = f2bf(eb[(size_t)n * F_]);
        }
    }

    fragC oacc[4];
    #pragma unroll
    for (int q = 0; q < 4; ++q) oacc[q] = fragC{0.f, 0.f, 0.f, 0.f};

    STAGE(0);

    #pragma unroll 1
    for (int hc = 0; hc < 4; ++hc) {
        int hb0 = hc * HC;

        fragC acc2[8];
        #pragma unroll
        for (int q = 0; q < 8; ++q) acc2[q] = fragC{0.f, 0.f, 0.f, 0.f};

        #pragma unroll
        for (int kc = 0; kc < 4; ++kc) {
            int s = hc*4 + kc;
            // wbuf[s&1] loads were issued at step s-1 (or prologue); drain + sync,
            // then immediately issue next-step loads so they fly under compute.
            asm volatile("s_waitcnt vmcnt(0)" ::: "memory");
            __syncthreads();
            if (s + 1 < 16) STAGE(s + 1);

            #pragma unroll
            for (int kh = 0; kh < 2; ++kh) {
                #pragma unroll
                for (int q = 0; q < 8; ++q) {
                    int hl = q*16 + lr;
                    int ns = (kh*32 + lg*8) ^ ((hl & 7) << 3);
                    fragA b = *(const fragA*)&wbuf[s & 1][hl][ns];
                    acc2[q] = __builtin_amdgcn_mfma_f32_16x16x32_bf16(
                        a[kc*2 + kh], b, acc2[q], 0, 0, 0);
                }
            }
        }

        // bias + relu -> hlds (bf16). hlds rows are wave-private: no barriers.
        #pragma unroll
        for (int q = 0; q < 8; ++q) {
            int hcol = q*16 + lr;
            float bv = b1[p*H_ + hb0 + hcol];
            #pragma unroll
            for (int r = 0; r < 4; ++r) {
                int frow = w*16 + lg*4 + r;
                float v = acc2[q][r] + bv;
                v = fmaxf(v, 0.f);
                hlds[frow][hcol ^ hswz(frow)] = f2bf(v);
            }
        }

        // stage 3: oacc += h_chunk @ W2[chunk]  (reads only this wave's hlds rows)
        #pragma unroll
        for (int k3 = 0; k3 < 4; ++k3) {
            int frow = w*16 + lr;
            int hloc = k3*32 + lg*8;
            fragA a3 = *(const fragA*)&hlds[frow][hloc ^ hswz(frow)];
            #pragma unroll
            for (int q3 = 0; q3 < 4; ++q3) {
                const short* wsrc = w2t + ((size_t)(p*O_ + q3*16 + lr)) * H_
                                        + hb0 + k3*32 + lg*8;
                fragA b3 = *(const fragA*)wsrc;
                oacc[q3] = __builtin_amdgcn_mfma_f32_16x16x32_bf16(
                    a3, b3, oacc[q3], 0, 0, 0);
            }
        }
    }

    // epilogue: + b2, f32 store
    #pragma unroll
    for (int q3 = 0; q3 < 4; ++q3) {
        int o = q3*16 + lr;
        float bv = b2[p*O_ + o];
        #pragma unroll
        for (int r = 0; r < 4; ++r) {
            int f = f0 + w*16 + lg*4 + r;
            out[((size_t)(p*F_ + f)) * O_ + o] = oacc[q3][r] + bv;
        }
    }
}

extern "C" void kernel_launch(void* const* d_in, const int* in_sizes, int n_in,
                              void* d_out, int out_size, void* d_ws, size_t ws_size,
                              hipStream_t stream) {
    const float* lpls = (const float*)d_in[0];   // [P][N][N]
    const float* expm = (const float*)d_in[1];   // [P][N][F]
    const float* W1   = (const float*)d_in[2];   // [P][N][H]
    const float* b1   = (const float*)d_in[3];   // [P][H]
    const float* W2   = (const float*)d_in[4];   // [P][H][O]
    const float* b2   = (const float*)d_in[5];   // [P][O]
    float* outp = (float*)d_out;

    // workspace layout (bf16 buffers), total 45,088,768 B
    char* base = (char*)d_ws;
    short* lplsT = (short*)(base);                         // [P][N][N]  8 MB
    short* w1T   = (short*)(base + 8388608);               // [P][H][N] 16 MB
    short* w1t   = (short*)(base + 8388608 + 16777216);    // [P][H][N] 16 MB
    short* w2t   = (short*)(base + 8388608 + 2*16777216);  // [P][O][H]  4 MB

    // 1) transposes + bf16 convert
    k_transpose_cvt<<<dim3(N_/32, N_/32, P_), 256, 0, stream>>>(lpls, lplsT, N_, N_);
    k_transpose_cvt<<<dim3(H_/32, N_/32, P_), 256, 0, stream>>>(W1,   w1T,   N_, H_);
    k_transpose_cvt<<<dim3(O_/32, H_/32, P_), 256, 0, stream>>>(W2,   w2t,   H_, O_);
    // 2) fold the Laplacian into W1:  w1t = (lpls^T @ W1)^T
    k_fold<<<512, 256, 0, stream>>>(w1T, lplsT, w1t);
    // 3) fused MLP over cells
    k_mlp<<<P_ * (F_ / FT), 512, 0, stream>>>(expm, w1t, b1, w2t, b2, outp);
}